// Round 5
// baseline (102.799 us; speedup 1.0000x reference)
//
#include <hip/hip_runtime.h>
#include <math.h>

typedef unsigned short u16;
typedef __attribute__((ext_vector_type(8))) short bf16x8;  // 8 bf16 (4 VGPRs)
typedef __attribute__((ext_vector_type(4))) float f32x4;   // 4 f32 acc

#define DEVI __device__ __forceinline__

constexpr int NV = 4;
constexpr int NB = 4096;
constexpr int ND = 1024;
constexpr int NH = 512;
constexpr int NC = 50;
constexpr int NSAMP = 10000;
constexpr int NCP = 64;  // padded C for MFMA N-dim

DEVI u16 to_bf16(float f) {
  union { float f; unsigned u; } v; v.f = f;
  unsigned r = v.u + 0x7fffu + ((v.u >> 16) & 1u);  // RNE
  return (u16)(r >> 16);
}

DEVI float wsum(float x) {
#pragma unroll
  for (int m = 32; m > 0; m >>= 1) x += __shfl_xor(x, m, 64);
  return x;
}

#define GLD_LDS16(gsrc, ldst)                                                  \
  __builtin_amdgcn_global_load_lds(                                            \
      (const __attribute__((address_space(1))) void*)(gsrc),                   \
      (__attribute__((address_space(3))) void*)(ldst), 16, 0, 0)

// ---------------------------------------------------------------- convert x
__global__ __launch_bounds__(256) void k_convert_x(const float* __restrict__ x,
                                                   u16* __restrict__ xb) {
  const long n4 = (long)NV * NB * ND / 4;
  long i = (long)blockIdx.x * blockDim.x + threadIdx.x;
  const long stride = (long)gridDim.x * blockDim.x;
  for (; i < n4; i += stride) {
    float4 f = ((const float4*)x)[i];
    ushort4 o;
    o.x = to_bf16(f.x); o.y = to_bf16(f.y);
    o.z = to_bf16(f.z); o.w = to_bf16(f.w);
    ((ushort4*)xb)[i] = o;
  }
}

// ------------------------------------------------- W1 (V,D,H) -> (V,H,D) bf16
__global__ __launch_bounds__(256) void k_transpose_w1(const float* __restrict__ W1,
                                                      u16* __restrict__ W1T) {
  __shared__ float tile[32][33];
  const int v = blockIdx.z;
  const int d0 = blockIdx.x * 32;
  const int h0 = blockIdx.y * 32;
  const float* src = W1 + (size_t)v * ND * NH;
  u16* dst = W1T + (size_t)v * NH * ND;
  const int tx = threadIdx.x, ty = threadIdx.y;  // (32, 8)
#pragma unroll
  for (int j = 0; j < 32; j += 8)
    tile[ty + j][tx] = src[(size_t)(d0 + ty + j) * NH + h0 + tx];
  __syncthreads();
#pragma unroll
  for (int j = 0; j < 32; j += 8)
    dst[(size_t)(h0 + ty + j) * ND + d0 + tx] = to_bf16(tile[tx][ty + j]);
}

// -------------------------------------- W2 (V,H,C) -> (V,64,H) bf16, zero-pad
__global__ __launch_bounds__(256) void k_prep_w2(const float* __restrict__ W2,
                                                 u16* __restrict__ W2T) {
  int i = blockIdx.x * blockDim.x + threadIdx.x;
  if (i >= NV * NCP * NH) return;
  int h = i % NH;
  int c = (i / NH) % NCP;
  int v = i / (NCP * NH);
  float val = (c < NC) ? W2[((size_t)v * NH + h) * NC + c] : 0.f;
  W2T[i] = to_bf16(val);
}

// --------------------------------------------------- GEMM1: h=relu(x@W1+b1)
// A = xb (M=NB x K=ND row-major), B storage = W1T (N=NH x K=ND row-major)
__global__ __launch_bounds__(256) void k_gemm1(const u16* __restrict__ Xb,
                                               const u16* __restrict__ W1T,
                                               const float* __restrict__ b1,
                                               u16* __restrict__ Hb) {
  constexpr int BM = 128, BN = 128, BK = 32;
  const int v = blockIdx.z;
  const int m0 = blockIdx.x * BM;
  const int n0 = blockIdx.y * BN;
  __shared__ u16 As[BM][BK];  // 8 KB
  __shared__ u16 Bs[BN][BK];  // 8 KB
  const u16* Ag = Xb + (size_t)v * NB * ND + (size_t)m0 * ND;
  const u16* Bg = W1T + (size_t)v * NH * ND + (size_t)n0 * ND;
  const int tid = threadIdx.x;
  const int lane = tid & 63;
  const int wv = tid >> 6;            // 0..3
  const int wr = wv >> 1, wc = wv & 1;
  const int r = tid >> 2;             // 0..63 staging row
  const int c8 = (tid & 3) * 8;       // staging col (elements)

  f32x4 acc[4][4] = {};

  for (int k0 = 0; k0 < ND; k0 += BK) {
    __syncthreads();  // previous iter's reads done before overwrite
    GLD_LDS16(Ag + (size_t)r * ND + k0 + c8,        &As[r][c8]);
    GLD_LDS16(Ag + (size_t)(r + 64) * ND + k0 + c8, &As[r + 64][c8]);
    GLD_LDS16(Bg + (size_t)r * ND + k0 + c8,        &Bs[r][c8]);
    GLD_LDS16(Bg + (size_t)(r + 64) * ND + k0 + c8, &Bs[r + 64][c8]);
    __syncthreads();  // compiler drains vmcnt(0) before barrier

    const int fr = lane & 15;
    const int kb = (lane >> 4) * 8;
    bf16x8 af[4], bf[4];
#pragma unroll
    for (int mi = 0; mi < 4; ++mi)
      af[mi] = *(const bf16x8*)&As[wr * 64 + mi * 16 + fr][kb];
#pragma unroll
    for (int ni = 0; ni < 4; ++ni)
      bf[ni] = *(const bf16x8*)&Bs[wc * 64 + ni * 16 + fr][kb];
#pragma unroll
    for (int mi = 0; mi < 4; ++mi)
#pragma unroll
      for (int ni = 0; ni < 4; ++ni)
        acc[mi][ni] = __builtin_amdgcn_mfma_f32_16x16x32_bf16(
            af[mi], bf[ni], acc[mi][ni], 0, 0, 0);
  }

  // C/D layout (verified): col = lane&15, row = (lane>>4)*4 + reg
  const int frow = (lane >> 4) * 4;
  const int fcol = lane & 15;
#pragma unroll
  for (int mi = 0; mi < 4; ++mi) {
#pragma unroll
    for (int ni = 0; ni < 4; ++ni) {
      const int n = n0 + wc * 64 + ni * 16 + fcol;
      const float bias = b1[v * NH + n];
#pragma unroll
      for (int j = 0; j < 4; ++j) {
        const int m = m0 + wr * 64 + mi * 16 + frow + j;
        float val = fmaxf(acc[mi][ni][j] + bias, 0.f);
        Hb[(size_t)v * NB * NH + (size_t)m * NH + n] = to_bf16(val);
      }
    }
  }
}

// -------------------------------- GEMM2: evidence = softplus(h@W2+b2), N=64
__global__ __launch_bounds__(256) void k_gemm2(const u16* __restrict__ Hb,
                                               const u16* __restrict__ W2T,
                                               const float* __restrict__ b2,
                                               float* __restrict__ out_ev) {
  constexpr int BM = 64, BK = 32;
  const int v = blockIdx.z;
  const int m0 = blockIdx.x * BM;
  __shared__ u16 As[BM][BK];    // 4 KB
  __shared__ u16 Bs[NCP][BK];   // 4 KB
  const u16* Ag = Hb + (size_t)v * NB * NH + (size_t)m0 * NH;
  const u16* Bg = W2T + (size_t)v * NCP * NH;
  const int tid = threadIdx.x;
  const int lane = tid & 63;
  const int wv = tid >> 6;
  const int r = tid >> 2;
  const int c8 = (tid & 3) * 8;

  f32x4 acc[4] = {};

  for (int k0 = 0; k0 < NH; k0 += BK) {
    __syncthreads();
    GLD_LDS16(Ag + (size_t)r * NH + k0 + c8, &As[r][c8]);
    GLD_LDS16(Bg + (size_t)r * NH + k0 + c8, &Bs[r][c8]);
    __syncthreads();

    const int fr = lane & 15;
    const int kb = (lane >> 4) * 8;
    bf16x8 af = *(const bf16x8*)&As[wv * 16 + fr][kb];
#pragma unroll
    for (int ni = 0; ni < 4; ++ni) {
      bf16x8 bf = *(const bf16x8*)&Bs[ni * 16 + fr][kb];
      acc[ni] = __builtin_amdgcn_mfma_f32_16x16x32_bf16(af, bf, acc[ni], 0, 0, 0);
    }
  }

  const int frow = (lane >> 4) * 4;
  const int fcol = lane & 15;
#pragma unroll
  for (int ni = 0; ni < 4; ++ni) {
    const int n = ni * 16 + fcol;
    if (n < NC) {
      const float bias = b2[v * NC + n];
#pragma unroll
      for (int j = 0; j < 4; ++j) {
        const int m = m0 + wv * 16 + frow + j;
        float x = acc[ni][j] + bias;
        // stable softplus, matches jax.nn.softplus
        float sp = fmaxf(x, 0.f) + log1pf(expf(-fabsf(x)));
        out_ev[(size_t)v * NB * NC + (size_t)m * NC + n] = sp;
      }
    }
  }
}

// --------------------- transferred[v,b,d] = sum_c ev[v,b,c]*M[v,idx[b],c,d]
__global__ __launch_bounds__(256) void k_transfer(const float* __restrict__ evf,
                                                  const float* __restrict__ mats,
                                                  const int* __restrict__ idx,
                                                  float* __restrict__ out_tr) {
  const int gw = blockIdx.x * 4 + (threadIdx.x >> 6);  // global wave id
  const int lane = threadIdx.x & 63;
  if (gw >= NV * NB) return;
  const int v = gw >> 12;          // NB = 4096 = 2^12
  const int b = gw & (NB - 1);
  const float* e = evf + ((size_t)v * NB + b) * NC;
  const float* M = mats + ((size_t)v * NSAMP + idx[b]) * NC * NC;
  if (lane < NC) {
    float acc = 0.f;
#pragma unroll
    for (int c = 0; c < NC; ++c)
      acc = fmaf(e[c], M[c * NC + lane], acc);
    out_tr[((size_t)v * NB + b) * NC + lane] = acc;
  }
}

// ------------------------------------------- sequential DS combine, 4 views
__global__ __launch_bounds__(256) void k_combine(const float* __restrict__ trf,
                                                 float* __restrict__ out_ea) {
  const int b = blockIdx.x * 4 + (threadIdx.x >> 6);
  const int lane = threadIdx.x & 63;
  if (b >= NB) return;
  const bool act = lane < NC;
  const float Kf = (float)NC;

  float ta[NV];
#pragma unroll
  for (int v = 0; v < NV; ++v)
    ta[v] = act ? trf[((size_t)v * NB + b) * NC + lane] + 1.0f : 0.0f;

  float alpha = ta[0];
#pragma unroll
  for (int v = 1; v < NV; ++v) {
    float a2 = ta[v];
    float S1 = wsum(act ? alpha : 0.f);
    float S2 = wsum(act ? a2 : 0.f);
    float b1v = act ? (alpha - 1.f) / S1 : 0.f;
    float b2v = act ? (a2 - 1.f) / S2 : 0.f;
    float u1 = Kf / S1, u2 = Kf / S2;
    float sb1 = wsum(b1v);
    float sb2 = wsum(b2v);
    float sb12 = wsum(b1v * b2v);
    float Cconf = sb1 * sb2 - sb12;
    float denom = 1.f - Cconf;
    float b_a = (b1v * b2v + b1v * u2 + b2v * u1) / denom;
    float u_a = u1 * u2 / denom;
    float S_a = Kf / u_a;
    alpha = b_a * S_a + 1.f;  // e_a + 1
  }
  if (act) out_ea[(size_t)b * NC + lane] = alpha - 1.f;
}

// ---------------------------------------------------------------------------
extern "C" void kernel_launch(void* const* d_in, const int* in_sizes, int n_in,
                              void* d_out, int out_size, void* d_ws, size_t ws_size,
                              hipStream_t stream) {
  // Bind inputs BY ELEMENT COUNT (all distinct) — immune to order changes.
  const float *x = nullptr, *W1 = nullptr, *b1 = nullptr, *W2 = nullptr,
              *b2 = nullptr, *mats = nullptr;
  const int* idx = nullptr;
  for (int i = 0; i < n_in; ++i) {
    switch (in_sizes[i]) {
      case 16777216:  x    = (const float*)d_in[i]; break;  // V*B*D
      case 4096:      idx  = (const int*)d_in[i];   break;  // B
      case 2097152:   W1   = (const float*)d_in[i]; break;  // V*D*H
      case 2048:      b1   = (const float*)d_in[i]; break;  // V*H
      case 102400:    W2   = (const float*)d_in[i]; break;  // V*H*C
      case 200:       b2   = (const float*)d_in[i]; break;  // V*C
      case 100000000: mats = (const float*)d_in[i]; break;  // V*S*C*C
      default: break;
    }
  }
  if (!x || !idx || !W1 || !b1 || !W2 || !b2 || !mats) return;

  char* ws = (char*)d_ws;
  // ws layout (bytes): xb bf16 33554432; w1t bf16 4194304; w2t bf16 262144;
  // hb bf16 16777216 -> total ~54.8 MB
  u16* xb  = (u16*)(ws + 0);
  u16* w1t = (u16*)(ws + 33554432);
  u16* w2t = (u16*)(ws + 37748736);
  u16* hb  = (u16*)(ws + 38010880);

  // d_out is FLOAT32: [transferred (V,B,C) | evidence_a (B,C) | evidence (V,B,C)]
  float* out_tr = (float*)d_out;
  float* out_ea = out_tr + (size_t)NV * NB * NC;
  float* out_ev = out_ea + (size_t)NB * NC;

  k_convert_x<<<4096, 256, 0, stream>>>(x, xb);
  k_transpose_w1<<<dim3(ND / 32, NH / 32, NV), dim3(32, 8), 0, stream>>>(W1, w1t);
  k_prep_w2<<<(NV * NCP * NH + 255) / 256, 256, 0, stream>>>(W2, w2t);
  k_gemm1<<<dim3(NB / 128, NH / 128, NV), 256, 0, stream>>>(xb, w1t, b1, hb);
  k_gemm2<<<dim3(NB / 64, 1, NV), 256, 0, stream>>>(hb, w2t, b2, out_ev);
  k_transfer<<<NV * NB / 4, 256, 0, stream>>>(out_ev, mats, idx, out_tr);
  k_combine<<<NB / 4, 256, 0, stream>>>(out_tr, out_ea);
}

// Round 6
// 99.219 us; speedup vs baseline: 1.0361x; 1.0361x over previous
//
#include <hip/hip_runtime.h>
#include <math.h>

typedef unsigned short u16;
typedef __attribute__((ext_vector_type(8))) short bf16x8;  // 8 bf16 (4 VGPRs)
typedef __attribute__((ext_vector_type(4))) float f32x4;   // 4 f32 acc

#define DEVI __device__ __forceinline__

constexpr int NV = 4;
constexpr int NB = 4096;
constexpr int ND = 1024;
constexpr int NH = 512;
constexpr int NC = 50;
constexpr int NSAMP = 10000;
constexpr int NCP = 64;  // padded C for MFMA N-dim

DEVI u16 to_bf16(float f) {
  union { float f; unsigned u; } v; v.f = f;
  unsigned r = v.u + 0x7fffu + ((v.u >> 16) & 1u);  // RNE
  return (u16)(r >> 16);
}

DEVI float wsum(float x) {
#pragma unroll
  for (int m = 32; m > 0; m >>= 1) x += __shfl_xor(x, m, 64);
  return x;
}

#define GLD_LDS16(gsrc, ldst)                                                  \
  __builtin_amdgcn_global_load_lds(                                            \
      (const __attribute__((address_space(1))) void*)(gsrc),                   \
      (__attribute__((address_space(3))) void*)(ldst), 16, 0, 0)

// ------------------------------------------------- W1 (V,D,H) -> (V,H,D) bf16
__global__ __launch_bounds__(256) void k_transpose_w1(const float* __restrict__ W1,
                                                      u16* __restrict__ W1T) {
  __shared__ float tile[32][33];
  const int v = blockIdx.z;
  const int d0 = blockIdx.x * 32;
  const int h0 = blockIdx.y * 32;
  const float* src = W1 + (size_t)v * ND * NH;
  u16* dst = W1T + (size_t)v * NH * ND;
  const int tx = threadIdx.x, ty = threadIdx.y;  // (32, 8)
#pragma unroll
  for (int j = 0; j < 32; j += 8)
    tile[ty + j][tx] = src[(size_t)(d0 + ty + j) * NH + h0 + tx];
  __syncthreads();
#pragma unroll
  for (int j = 0; j < 32; j += 8)
    dst[(size_t)(h0 + ty + j) * ND + d0 + tx] = to_bf16(tile[tx][ty + j]);
}

// -------------------------------------- W2 (V,H,C) -> (V,64,H) bf16, zero-pad
__global__ __launch_bounds__(256) void k_prep_w2(const float* __restrict__ W2,
                                                 u16* __restrict__ W2T) {
  int i = blockIdx.x * blockDim.x + threadIdx.x;
  if (i >= NV * NCP * NH) return;
  int h = i % NH;
  int c = (i / NH) % NCP;
  int v = i / (NCP * NH);
  float val = (c < NC) ? W2[((size_t)v * NH + h) * NC + c] : 0.f;
  W2T[i] = to_bf16(val);
}

// --------------------------------------------------- GEMM1: h=relu(x@W1+b1)
// A = x (f32, M=NB x K=ND row-major) converted to bf16 during staging.
// B storage = W1T (bf16, N=NH x K=ND row-major), staged via global_load_lds.
__global__ __launch_bounds__(256) void k_gemm1(const float* __restrict__ Xf,
                                               const u16* __restrict__ W1T,
                                               const float* __restrict__ b1,
                                               u16* __restrict__ Hb) {
  constexpr int BM = 128, BN = 128, BK = 32;
  const int v = blockIdx.z;
  const int m0 = blockIdx.x * BM;
  const int n0 = blockIdx.y * BN;
  __shared__ u16 As[BM][BK];  // 8 KB
  __shared__ u16 Bs[BN][BK];  // 8 KB
  const float* Ag = Xf + (size_t)v * NB * ND + (size_t)m0 * ND;
  const u16* Bg = W1T + (size_t)v * NH * ND + (size_t)n0 * ND;
  const int tid = threadIdx.x;
  const int lane = tid & 63;
  const int wv = tid >> 6;            // 0..3
  const int wr = wv >> 1, wc = wv & 1;
  const int rB = tid >> 2;            // B staging row
  const int cB = (tid & 3) * 8;       // B staging col (elements)
  const int rA = tid >> 1;            // A staging row (2 threads/row)
  const int cA = (tid & 1) * 16;      // A staging col (16 f32 per thread)

  f32x4 acc[4][4] = {};

  for (int k0 = 0; k0 < ND; k0 += BK) {
    __syncthreads();  // previous iter's reads done before overwrite
    // B: async global->LDS (bf16 already)
    GLD_LDS16(Bg + (size_t)rB * ND + k0 + cB,        &Bs[rB][cB]);
    GLD_LDS16(Bg + (size_t)(rB + 64) * ND + k0 + cB, &Bs[rB + 64][cB]);
    // A: f32 -> regs -> bf16 -> LDS
    {
      const float* ap = Ag + (size_t)rA * ND + k0 + cA;
      float4 f0 = ((const float4*)ap)[0];
      float4 f1 = ((const float4*)ap)[1];
      float4 f2 = ((const float4*)ap)[2];
      float4 f3 = ((const float4*)ap)[3];
      ushort4 u0, u1, u2, u3;
      u0.x = to_bf16(f0.x); u0.y = to_bf16(f0.y); u0.z = to_bf16(f0.z); u0.w = to_bf16(f0.w);
      u1.x = to_bf16(f1.x); u1.y = to_bf16(f1.y); u1.z = to_bf16(f1.z); u1.w = to_bf16(f1.w);
      u2.x = to_bf16(f2.x); u2.y = to_bf16(f2.y); u2.z = to_bf16(f2.z); u2.w = to_bf16(f2.w);
      u3.x = to_bf16(f3.x); u3.y = to_bf16(f3.y); u3.z = to_bf16(f3.z); u3.w = to_bf16(f3.w);
      *(ushort4*)&As[rA][cA]     = u0;
      *(ushort4*)&As[rA][cA + 4] = u1;
      *(ushort4*)&As[rA][cA + 8] = u2;
      *(ushort4*)&As[rA][cA + 12]= u3;
    }
    __syncthreads();  // drains vmcnt+lgkmcnt before use

    const int fr = lane & 15;
    const int kb = (lane >> 4) * 8;
    bf16x8 af[4], bf[4];
#pragma unroll
    for (int mi = 0; mi < 4; ++mi)
      af[mi] = *(const bf16x8*)&As[wr * 64 + mi * 16 + fr][kb];
#pragma unroll
    for (int ni = 0; ni < 4; ++ni)
      bf[ni] = *(const bf16x8*)&Bs[wc * 64 + ni * 16 + fr][kb];
#pragma unroll
    for (int mi = 0; mi < 4; ++mi)
#pragma unroll
      for (int ni = 0; ni < 4; ++ni)
        acc[mi][ni] = __builtin_amdgcn_mfma_f32_16x16x32_bf16(
            af[mi], bf[ni], acc[mi][ni], 0, 0, 0);
  }

  // C/D layout (verified): col = lane&15, row = (lane>>4)*4 + reg
  const int frow = (lane >> 4) * 4;
  const int fcol = lane & 15;
#pragma unroll
  for (int mi = 0; mi < 4; ++mi) {
#pragma unroll
    for (int ni = 0; ni < 4; ++ni) {
      const int n = n0 + wc * 64 + ni * 16 + fcol;
      const float bias = b1[v * NH + n];
#pragma unroll
      for (int j = 0; j < 4; ++j) {
        const int m = m0 + wr * 64 + mi * 16 + frow + j;
        float val = fmaxf(acc[mi][ni][j] + bias, 0.f);
        Hb[(size_t)v * NB * NH + (size_t)m * NH + n] = to_bf16(val);
      }
    }
  }
}

// -------------------------------- GEMM2: evidence = softplus(h@W2+b2), N=64
__global__ __launch_bounds__(256) void k_gemm2(const u16* __restrict__ Hb,
                                               const u16* __restrict__ W2T,
                                               const float* __restrict__ b2,
                                               float* __restrict__ out_ev) {
  constexpr int BM = 64, BK = 32;
  const int v = blockIdx.z;
  const int m0 = blockIdx.x * BM;
  __shared__ u16 As[BM][BK];    // 4 KB
  __shared__ u16 Bs[NCP][BK];   // 4 KB
  const u16* Ag = Hb + (size_t)v * NB * NH + (size_t)m0 * NH;
  const u16* Bg = W2T + (size_t)v * NCP * NH;
  const int tid = threadIdx.x;
  const int lane = tid & 63;
  const int wv = tid >> 6;
  const int r = tid >> 2;
  const int c8 = (tid & 3) * 8;

  f32x4 acc[4] = {};

  for (int k0 = 0; k0 < NH; k0 += BK) {
    __syncthreads();
    GLD_LDS16(Ag + (size_t)r * NH + k0 + c8, &As[r][c8]);
    GLD_LDS16(Bg + (size_t)r * NH + k0 + c8, &Bs[r][c8]);
    __syncthreads();

    const int fr = lane & 15;
    const int kb = (lane >> 4) * 8;
    bf16x8 af = *(const bf16x8*)&As[wv * 16 + fr][kb];
#pragma unroll
    for (int ni = 0; ni < 4; ++ni) {
      bf16x8 bf = *(const bf16x8*)&Bs[ni * 16 + fr][kb];
      acc[ni] = __builtin_amdgcn_mfma_f32_16x16x32_bf16(af, bf, acc[ni], 0, 0, 0);
    }
  }

  const int frow = (lane >> 4) * 4;
  const int fcol = lane & 15;
#pragma unroll
  for (int ni = 0; ni < 4; ++ni) {
    const int n = ni * 16 + fcol;
    if (n < NC) {
      const float bias = b2[v * NC + n];
#pragma unroll
      for (int j = 0; j < 4; ++j) {
        const int m = m0 + wv * 16 + frow + j;
        float x = acc[ni][j] + bias;
        // stable softplus, matches jax.nn.softplus
        float sp = fmaxf(x, 0.f) + log1pf(expf(-fabsf(x)));
        out_ev[(size_t)v * NB * NC + (size_t)m * NC + n] = sp;
      }
    }
  }
}

// ------------- fused transfer + DS-combine: wave = one batch row b
// transferred[v,b,:] = ev[v,b,:] @ M[v,idx[b]]; then sequential ds_combin.
__global__ __launch_bounds__(256) void k_tc(const float* __restrict__ evf,
                                            const float* __restrict__ mats,
                                            const int* __restrict__ idx,
                                            float* __restrict__ out_tr,
                                            float* __restrict__ out_ea) {
  const int b = blockIdx.x * 4 + (threadIdx.x >> 6);
  const int lane = threadIdx.x & 63;
  if (b >= NB) return;
  const bool act = lane < NC;
  const float Kf = (float)NC;
  const int ix = idx[b];

  float ta[NV];
#pragma unroll
  for (int v = 0; v < NV; ++v) {
    float acc = 0.f;
    if (act) {
      const float* e = evf + ((size_t)v * NB + b) * NC;
      const float* M = mats + ((size_t)v * NSAMP + ix) * NC * NC;
#pragma unroll
      for (int c = 0; c < NC; ++c)
        acc = fmaf(e[c], M[c * NC + lane], acc);
      out_tr[((size_t)v * NB + b) * NC + lane] = acc;
    }
    ta[v] = act ? acc + 1.0f : 0.0f;
  }

  float alpha = ta[0];
#pragma unroll
  for (int v = 1; v < NV; ++v) {
    float a2 = ta[v];
    float S1 = wsum(act ? alpha : 0.f);
    float S2 = wsum(act ? a2 : 0.f);
    float b1v = act ? (alpha - 1.f) / S1 : 0.f;
    float b2v = act ? (a2 - 1.f) / S2 : 0.f;
    float u1 = Kf / S1, u2 = Kf / S2;
    float sb1 = wsum(b1v);
    float sb2 = wsum(b2v);
    float sb12 = wsum(b1v * b2v);
    float Cconf = sb1 * sb2 - sb12;
    float denom = 1.f - Cconf;
    float b_a = (b1v * b2v + b1v * u2 + b2v * u1) / denom;
    float u_a = u1 * u2 / denom;
    float S_a = Kf / u_a;
    alpha = b_a * S_a + 1.f;  // e_a + 1
  }
  if (act) out_ea[(size_t)b * NC + lane] = alpha - 1.f;
}

// ---------------------------------------------------------------------------
extern "C" void kernel_launch(void* const* d_in, const int* in_sizes, int n_in,
                              void* d_out, int out_size, void* d_ws, size_t ws_size,
                              hipStream_t stream) {
  // Bind inputs BY ELEMENT COUNT (all distinct) — immune to order changes.
  const float *x = nullptr, *W1 = nullptr, *b1 = nullptr, *W2 = nullptr,
              *b2 = nullptr, *mats = nullptr;
  const int* idx = nullptr;
  for (int i = 0; i < n_in; ++i) {
    switch (in_sizes[i]) {
      case 16777216:  x    = (const float*)d_in[i]; break;  // V*B*D
      case 4096:      idx  = (const int*)d_in[i];   break;  // B
      case 2097152:   W1   = (const float*)d_in[i]; break;  // V*D*H
      case 2048:      b1   = (const float*)d_in[i]; break;  // V*H
      case 102400:    W2   = (const float*)d_in[i]; break;  // V*H*C
      case 200:       b2   = (const float*)d_in[i]; break;  // V*C
      case 100000000: mats = (const float*)d_in[i]; break;  // V*S*C*C
      default: break;
    }
  }
  if (!x || !idx || !W1 || !b1 || !W2 || !b2 || !mats) return;

  char* ws = (char*)d_ws;
  // ws layout (bytes): w1t bf16 4194304; w2t bf16 262144; hb bf16 16777216
  u16* w1t = (u16*)(ws + 0);
  u16* w2t = (u16*)(ws + 4194304);
  u16* hb  = (u16*)(ws + 4456448);

  // d_out is FLOAT32: [transferred (V,B,C) | evidence_a (B,C) | evidence (V,B,C)]
  float* out_tr = (float*)d_out;
  float* out_ea = out_tr + (size_t)NV * NB * NC;
  float* out_ev = out_ea + (size_t)NB * NC;

  k_transpose_w1<<<dim3(ND / 32, NH / 32, NV), dim3(32, 8), 0, stream>>>(W1, w1t);
  k_prep_w2<<<(NV * NCP * NH + 255) / 256, 256, 0, stream>>>(W2, w2t);
  k_gemm1<<<dim3(NB / 128, NH / 128, NV), 256, 0, stream>>>(x, w1t, b1, hb);
  k_gemm2<<<dim3(NB / 64, 1, NV), 256, 0, stream>>>(hb, w2t, b2, out_ev);
  k_tc<<<NB / 4, 256, 0, stream>>>(out_ev, mats, idx, out_tr, out_ea);
}

// Round 7
// 92.361 us; speedup vs baseline: 1.1130x; 1.0743x over previous
//
#include <hip/hip_runtime.h>
#include <hip/hip_bf16.h>
#include <math.h>

typedef unsigned short u16;
typedef __attribute__((ext_vector_type(8))) short bf16x8;  // 8 bf16 (4 VGPRs)
typedef __attribute__((ext_vector_type(4))) float f32x4;   // 4 f32 acc

#define DEVI __device__ __forceinline__

constexpr int NV = 4;
constexpr int NB = 4096;
constexpr int ND = 1024;
constexpr int NH = 512;
constexpr int NC = 50;
constexpr int NSAMP = 10000;
constexpr int NCP = 64;  // padded C for MFMA N-dim

DEVI u16 to_bf16(float f) {
  union { float f; unsigned u; } v; v.f = f;
  unsigned r = v.u + 0x7fffu + ((v.u >> 16) & 1u);  // RNE
  return (u16)(r >> 16);
}

// compiler-native cast: emits v_cvt (pairs to v_cvt_pk_bf16_f32), RNE
DEVI u16 cvt_bf16(float f) {
  __hip_bfloat16 h = __float2bfloat16(f);
  return *reinterpret_cast<u16*>(&h);
}

DEVI float wsum(float x) {
#pragma unroll
  for (int m = 32; m > 0; m >>= 1) x += __shfl_xor(x, m, 64);
  return x;
}

#define GLD_LDS16(gsrc, ldst)                                                  \
  __builtin_amdgcn_global_load_lds(                                            \
      (const __attribute__((address_space(1))) void*)(gsrc),                   \
      (__attribute__((address_space(3))) void*)(ldst), 16, 0, 0)

// ------------------------------------------------- W1 (V,D,H) -> (V,H,D) bf16
__global__ __launch_bounds__(256) void k_transpose_w1(const float* __restrict__ W1,
                                                      u16* __restrict__ W1T) {
  __shared__ float tile[32][33];
  const int v = blockIdx.z;
  const int d0 = blockIdx.x * 32;
  const int h0 = blockIdx.y * 32;
  const float* src = W1 + (size_t)v * ND * NH;
  u16* dst = W1T + (size_t)v * NH * ND;
  const int tx = threadIdx.x, ty = threadIdx.y;  // (32, 8)
#pragma unroll
  for (int j = 0; j < 32; j += 8)
    tile[ty + j][tx] = src[(size_t)(d0 + ty + j) * NH + h0 + tx];
  __syncthreads();
#pragma unroll
  for (int j = 0; j < 32; j += 8)
    dst[(size_t)(h0 + ty + j) * ND + d0 + tx] = to_bf16(tile[tx][ty + j]);
}

// -------------------------------------- W2 (V,H,C) -> (V,64,H) bf16, zero-pad
__global__ __launch_bounds__(256) void k_prep_w2(const float* __restrict__ W2,
                                                 u16* __restrict__ W2T) {
  int i = blockIdx.x * blockDim.x + threadIdx.x;
  if (i >= NV * NCP * NH) return;
  int h = i % NH;
  int c = (i / NH) % NCP;
  int v = i / (NCP * NH);
  float val = (c < NC) ? W2[((size_t)v * NH + h) * NC + c] : 0.f;
  W2T[i] = to_bf16(val);
}

// --------------------------------------------------- GEMM1: h=relu(x@W1+b1)
// A = x (f32) -> register prefetch (T14 split) -> cvt -> LDS bf16.
// B storage = W1T (bf16, N x K row-major), staged via async global_load_lds.
__global__ __launch_bounds__(256) void k_gemm1(const float* __restrict__ Xf,
                                               const u16* __restrict__ W1T,
                                               const float* __restrict__ b1,
                                               u16* __restrict__ Hb) {
  constexpr int BM = 128, BN = 128, BK = 32;
  const int v = blockIdx.z;
  const int m0 = blockIdx.x * BM;
  const int n0 = blockIdx.y * BN;
  __shared__ u16 As[BM][BK];  // 8 KB
  __shared__ u16 Bs[BN][BK];  // 8 KB
  const float* Ag = Xf + (size_t)v * NB * ND + (size_t)m0 * ND;
  const u16* Bg = W1T + (size_t)v * NH * ND + (size_t)n0 * ND;
  const int tid = threadIdx.x;
  const int lane = tid & 63;
  const int wv = tid >> 6;            // 0..3
  const int wr = wv >> 1, wc = wv & 1;
  const int rA = tid >> 3;            // 0..31 (+32*i); 8 threads/row
  const int cA = (tid & 7) * 4;       // 4 f32 per thread
  const int rB = tid >> 2;            // B staging row
  const int cB = (tid & 3) * 8;       // B staging col (elements)

  f32x4 acc[4][4] = {};

  // prologue: prefetch A-tile k0=0 into registers
  float4 pa[4];
#pragma unroll
  for (int i = 0; i < 4; ++i)
    pa[i] = *(const float4*)(Ag + (size_t)(rA + i * 32) * ND + cA);

  for (int k0 = 0; k0 < ND; k0 += BK) {
    __syncthreads();  // previous iter's LDS reads done before overwrite
    // A: registers (already arrived) -> cvt -> LDS. 8B/lane stride => 2-way
    // bank aliasing (free).
#pragma unroll
    for (int i = 0; i < 4; ++i) {
      ushort4 u;
      u.x = cvt_bf16(pa[i].x); u.y = cvt_bf16(pa[i].y);
      u.z = cvt_bf16(pa[i].z); u.w = cvt_bf16(pa[i].w);
      *(ushort4*)&As[rA + i * 32][cA] = u;
    }
    // B: async global->LDS (bf16 already)
    GLD_LDS16(Bg + (size_t)rB * ND + k0 + cB,        &Bs[rB][cB]);
    GLD_LDS16(Bg + (size_t)(rB + 64) * ND + k0 + cB, &Bs[rB + 64][cB]);
    __syncthreads();  // drains lgkm (ds_write) + vmcnt (gld_lds)

    // T14: issue NEXT tile's A loads now; latency hides under MFMA phase.
    if (k0 + BK < ND) {
#pragma unroll
      for (int i = 0; i < 4; ++i)
        pa[i] = *(const float4*)(Ag + (size_t)(rA + i * 32) * ND + k0 + BK + cA);
    }

    const int fr = lane & 15;
    const int kb = (lane >> 4) * 8;
    bf16x8 af[4], bf[4];
#pragma unroll
    for (int mi = 0; mi < 4; ++mi)
      af[mi] = *(const bf16x8*)&As[wr * 64 + mi * 16 + fr][kb];
#pragma unroll
    for (int ni = 0; ni < 4; ++ni)
      bf[ni] = *(const bf16x8*)&Bs[wc * 64 + ni * 16 + fr][kb];
#pragma unroll
    for (int mi = 0; mi < 4; ++mi)
#pragma unroll
      for (int ni = 0; ni < 4; ++ni)
        acc[mi][ni] = __builtin_amdgcn_mfma_f32_16x16x32_bf16(
            af[mi], bf[ni], acc[mi][ni], 0, 0, 0);
  }

  // C/D layout (verified): col = lane&15, row = (lane>>4)*4 + reg
  const int frow = (lane >> 4) * 4;
  const int fcol = lane & 15;
#pragma unroll
  for (int mi = 0; mi < 4; ++mi) {
#pragma unroll
    for (int ni = 0; ni < 4; ++ni) {
      const int n = n0 + wc * 64 + ni * 16 + fcol;
      const float bias = b1[v * NH + n];
#pragma unroll
      for (int j = 0; j < 4; ++j) {
        const int m = m0 + wr * 64 + mi * 16 + frow + j;
        float val = fmaxf(acc[mi][ni][j] + bias, 0.f);
        Hb[(size_t)v * NB * NH + (size_t)m * NH + n] = to_bf16(val);
      }
    }
  }
}

// -------------------------------- GEMM2: evidence = softplus(h@W2+b2), N=64
__global__ __launch_bounds__(256) void k_gemm2(const u16* __restrict__ Hb,
                                               const u16* __restrict__ W2T,
                                               const float* __restrict__ b2,
                                               float* __restrict__ out_ev) {
  constexpr int BM = 64, BK = 32;
  const int v = blockIdx.z;
  const int m0 = blockIdx.x * BM;
  __shared__ u16 As[BM][BK];    // 4 KB
  __shared__ u16 Bs[NCP][BK];   // 4 KB
  const u16* Ag = Hb + (size_t)v * NB * NH + (size_t)m0 * NH;
  const u16* Bg = W2T + (size_t)v * NCP * NH;
  const int tid = threadIdx.x;
  const int lane = tid & 63;
  const int wv = tid >> 6;
  const int r = tid >> 2;
  const int c8 = (tid & 3) * 8;

  f32x4 acc[4] = {};

  for (int k0 = 0; k0 < NH; k0 += BK) {
    __syncthreads();
    GLD_LDS16(Ag + (size_t)r * NH + k0 + c8, &As[r][c8]);
    GLD_LDS16(Bg + (size_t)r * NH + k0 + c8, &Bs[r][c8]);
    __syncthreads();

    const int fr = lane & 15;
    const int kb = (lane >> 4) * 8;
    bf16x8 af = *(const bf16x8*)&As[wv * 16 + fr][kb];
#pragma unroll
    for (int ni = 0; ni < 4; ++ni) {
      bf16x8 bf = *(const bf16x8*)&Bs[ni * 16 + fr][kb];
      acc[ni] = __builtin_amdgcn_mfma_f32_16x16x32_bf16(af, bf, acc[ni], 0, 0, 0);
    }
  }

  const int frow = (lane >> 4) * 4;
  const int fcol = lane & 15;
#pragma unroll
  for (int ni = 0; ni < 4; ++ni) {
    const int n = ni * 16 + fcol;
    if (n < NC) {
      const float bias = b2[v * NC + n];
#pragma unroll
      for (int j = 0; j < 4; ++j) {
        const int m = m0 + wv * 16 + frow + j;
        float x = acc[ni][j] + bias;
        // stable softplus, matches jax.nn.softplus
        float sp = fmaxf(x, 0.f) + log1pf(expf(-fabsf(x)));
        out_ev[(size_t)v * NB * NC + (size_t)m * NC + n] = sp;
      }
    }
  }
}

// ------------- fused transfer + DS-combine: wave = one batch row b
// transferred[v,b,:] = ev[v,b,:] @ M[v,idx[b]]; then sequential ds_combin.
__global__ __launch_bounds__(256) void k_tc(const float* __restrict__ evf,
                                            const float* __restrict__ mats,
                                            const int* __restrict__ idx,
                                            float* __restrict__ out_tr,
                                            float* __restrict__ out_ea) {
  const int b = blockIdx.x * 4 + (threadIdx.x >> 6);
  const int lane = threadIdx.x & 63;
  if (b >= NB) return;
  const bool act = lane < NC;
  const float Kf = (float)NC;
  const int ix = idx[b];

  float ta[NV];
#pragma unroll
  for (int v = 0; v < NV; ++v) {
    float acc = 0.f;
    if (act) {
      const float* e = evf + ((size_t)v * NB + b) * NC;
      const float* M = mats + ((size_t)v * NSAMP + ix) * NC * NC;
#pragma unroll
      for (int c = 0; c < NC; ++c)
        acc = fmaf(e[c], M[c * NC + lane], acc);
      out_tr[((size_t)v * NB + b) * NC + lane] = acc;
    }
    ta[v] = act ? acc + 1.0f : 0.0f;
  }

  float alpha = ta[0];
#pragma unroll
  for (int v = 1; v < NV; ++v) {
    float a2 = ta[v];
    float S1 = wsum(act ? alpha : 0.f);
    float S2 = wsum(act ? a2 : 0.f);
    float b1v = act ? (alpha - 1.f) / S1 : 0.f;
    float b2v = act ? (a2 - 1.f) / S2 : 0.f;
    float u1 = Kf / S1, u2 = Kf / S2;
    float sb1 = wsum(b1v);
    float sb2 = wsum(b2v);
    float sb12 = wsum(b1v * b2v);
    float Cconf = sb1 * sb2 - sb12;
    float denom = 1.f - Cconf;
    float b_a = (b1v * b2v + b1v * u2 + b2v * u1) / denom;
    float u_a = u1 * u2 / denom;
    float S_a = Kf / u_a;
    alpha = b_a * S_a + 1.f;  // e_a + 1
  }
  if (act) out_ea[(size_t)b * NC + lane] = alpha - 1.f;
}

// ---------------------------------------------------------------------------
extern "C" void kernel_launch(void* const* d_in, const int* in_sizes, int n_in,
                              void* d_out, int out_size, void* d_ws, size_t ws_size,
                              hipStream_t stream) {
  // Bind inputs BY ELEMENT COUNT (all distinct) — immune to order changes.
  const float *x = nullptr, *W1 = nullptr, *b1 = nullptr, *W2 = nullptr,
              *b2 = nullptr, *mats = nullptr;
  const int* idx = nullptr;
  for (int i = 0; i < n_in; ++i) {
    switch (in_sizes[i]) {
      case 16777216:  x    = (const float*)d_in[i]; break;  // V*B*D
      case 4096:      idx  = (const int*)d_in[i];   break;  // B
      case 2097152:   W1   = (const float*)d_in[i]; break;  // V*D*H
      case 2048:      b1   = (const float*)d_in[i]; break;  // V*H
      case 102400:    W2   = (const float*)d_in[i]; break;  // V*H*C
      case 200:       b2   = (const float*)d_in[i]; break;  // V*C
      case 100000000: mats = (const float*)d_in[i]; break;  // V*S*C*C
      default: break;
    }
  }
  if (!x || !idx || !W1 || !b1 || !W2 || !b2 || !mats) return;

  char* ws = (char*)d_ws;
  // ws layout (bytes): w1t bf16 4194304; w2t bf16 262144; hb bf16 16777216
  u16* w1t = (u16*)(ws + 0);
  u16* w2t = (u16*)(ws + 4194304);
  u16* hb  = (u16*)(ws + 4456448);

  // d_out is FLOAT32: [transferred (V,B,C) | evidence_a (B,C) | evidence (V,B,C)]
  float* out_tr = (float*)d_out;
  float* out_ea = out_tr + (size_t)NV * NB * NC;
  float* out_ev = out_ea + (size_t)NB * NC;

  k_transpose_w1<<<dim3(ND / 32, NH / 32, NV), dim3(32, 8), 0, stream>>>(W1, w1t);
  k_prep_w2<<<(NV * NCP * NH + 255) / 256, 256, 0, stream>>>(W2, w2t);
  k_gemm1<<<dim3(NB / 128, NH / 128, NV), 256, 0, stream>>>(x, w1t, b1, hb);
  k_gemm2<<<dim3(NB / 64, 1, NV), 256, 0, stream>>>(hb, w2t, b2, out_ev);
  k_tc<<<NB / 4, 256, 0, stream>>>(out_ev, mats, idx, out_tr, out_ea);
}